// Round 7
// baseline (211.019 us; speedup 1.0000x reference)
//
#include <hip/hip_runtime.h>
#include <hip/hip_bf16.h>

// Problem: out[32768,128] = sigmoid(x[32768,1024] @ W[1024,128] + b[128]), all fp32.
// R7: fixes BOTH historical defects at once:
//   (1) A loaded CONTIGUOUSLY (wave = 4 rows x 1KB lines), cvt->bf16 once, staged in
//       padded LDS tile (136B stride, 2-way banks = free), frags via ds_read_b128.
//   (2) W via global_load_lds DMA, double-buffered 32KB phases issued a FULL phase
//       (2 chunk-barriers) ahead -> W never stalls; A double-buffered, prefetched a
//       chunk ahead in named regs (constant-indexed, spill-proof).
// Grid 256 x 512 thr (8 waves x 16 rows = 128 rows/block, 1 block/CU, no tail).
// LDS = 2x32KB (W) + 2x17408B (A) = 100352 B.

typedef __bf16 bf16x8 __attribute__((ext_vector_type(8)));
typedef __bf16 bf16x4 __attribute__((ext_vector_type(4)));
typedef float  f32x4  __attribute__((ext_vector_type(4)));
typedef unsigned int u32_as1 __attribute__((address_space(1)));
typedef unsigned int u32_as3 __attribute__((address_space(3)));

#define DIM   1024
#define NT    128
#define BATCH 32768

#define WBUF(b) ((unsigned)(b) * 32768u)
#define ABUF(b) (65536u + (unsigned)(b) * 17408u)
#define LDS_TOTAL (65536 + 2 * 17408)   // 100352 B

// ---------------------------------------------------------------------------
// Prep: W[k][n] fp32 -> bf16 in B-fragment order (frag-linear in k-steps).
// wsW[ ((s*8 + c)*64 + lane)*8 + j ] = W[ s*32 + (lane>>4)*8 + j ][ c*16 + (lane&15) ]
// ---------------------------------------------------------------------------
__global__ __launch_bounds__(256) void prep_w(const float* __restrict__ W,
                                              __bf16* __restrict__ wsW) {
    int idx = blockIdx.x * 256 + threadIdx.x;   // 0 .. 131071
    int j = idx & 7;
    int l = (idx >> 3) & 63;
    int c = (idx >> 9) & 7;
    int s = idx >> 12;
    int k = s * 32 + (l >> 4) * 8 + j;
    int n = c * 16 + (l & 15);
    wsW[idx] = (__bf16)W[k * NT + n];
}

// ---------------------------------------------------------------------------
// Main GEMM. Wave tile 16 rows x 128 cols (acc = 32 VGPR).
// Chunk = 2 k-steps (64 k). Phase = 2 chunks (4 k-steps, 32KB of W frags).
// A-frag (16x16x32): lane holds A[m = lane&15][k = (lane>>4)*8 + j]
// B-frag:            lane holds B[k = (lane>>4)*8 + j][n = lane&15]
// C/D:               col = lane&15, row = (lane>>4)*4 + reg
// ---------------------------------------------------------------------------
__global__ __launch_bounds__(512) void gemm_bias_sigmoid(
        const float* __restrict__ x,
        const __hip_bfloat16* __restrict__ wsWh,
        const float* __restrict__ bias,
        float* __restrict__ out) {
    __shared__ __align__(16) unsigned char lds[LDS_TOTAL];
    const bf16x8* __restrict__ wsW8 = (const bf16x8*)wsWh;  // 16384 frags of 16B

    const int tid  = threadIdx.x;
    const int lane = tid & 63;
    const int wave = tid >> 6;        // 0..7
    const int q    = lane >> 4;
    const int r    = lane & 15;
    const int row0 = blockIdx.x * 128;

    // A staging map: thread covers rows (tid>>4) + 32*i (i=0..3), k-span kpos4..kpos4+3
    const int arow = tid >> 4;          // 0..31
    const int kpos = (tid & 15) * 4;    // fp32 k-offset within chunk (0..60)
    const float* xA = x + (size_t)(row0 + arow) * DIM + kpos;

    f32x4 acc[8];
#pragma unroll
    for (int c = 0; c < 8; ++c)
        acc[c] = (f32x4){0.f, 0.f, 0.f, 0.f};

    float4 aA[4], aB[4];   // named A prefetch sets; constant-indexed only

    auto wdma = [&](int ph) {           // stage W phase ph (32KB) via LDS-DMA
#pragma unroll
        for (int i = 0; i < 4; ++i) {
            const bf16x8* g = wsW8 + ((size_t)ph * 2048 + i * 512 + tid);
            __builtin_amdgcn_global_load_lds(
                (const u32_as1*)g,
                (u32_as3*)(lds + WBUF(ph & 1) + (unsigned)((i * 512 + tid) * 16)),
                16, 0, 0);
        }
    };
    auto loadA = [&](float4* dst, int c) {   // contiguous: 4 rows x 1KB per wave-inst
        const float* ap = xA + (size_t)c * 64;
        dst[0] = *(const float4*)ap;
        dst[1] = *(const float4*)(ap + 32 * DIM);
        dst[2] = *(const float4*)(ap + 64 * DIM);
        dst[3] = *(const float4*)(ap + 96 * DIM);
    };
    auto writeA = [&](const float4* src, int b) {
#pragma unroll
        for (int i = 0; i < 4; ++i) {
            bf16x4 v;
            v[0] = (__bf16)src[i].x; v[1] = (__bf16)src[i].y;
            v[2] = (__bf16)src[i].z; v[3] = (__bf16)src[i].w;
            *(bf16x4*)(lds + ABUF(b) +
                       (unsigned)(arow + 32 * i) * 136u + (unsigned)(kpos * 2)) = v;
        }
    };
    auto comp = [&](int p, int wb) {    // chunk with parity p of phase in Wbuf[wb]
#pragma unroll
        for (int sl = 0; sl < 2; ++sl) {
            const bf16x8 af = *(const bf16x8*)(lds + ABUF(p) +
                (unsigned)(wave * 16 + r) * 136u + (unsigned)(sl * 64 + q * 16));
#pragma unroll
            for (int cc = 0; cc < 8; ++cc) {
                const bf16x8 bf = *(const bf16x8*)(lds + WBUF(wb) +
                    (unsigned)(((p * 2 + sl) * 8 + cc) * 1024 + lane * 16));
                acc[cc] = __builtin_amdgcn_mfma_f32_16x16x32_bf16(af, bf, acc[cc], 0, 0, 0);
            }
        }
    };

    // ---------------- prologue ----------------
    wdma(0);                 // phase 0 -> Wbuf0
    loadA(aA, 0);            // chunk 0
    writeA(aA, 0);           // -> Abuf0 (waits its own loads only)
    loadA(aA, 1);            // chunk 1 -> regs (reuse after write)
    __syncthreads();         // W(0) + A(0) visible

    // ---------------- main: 8 iters x 2 chunks ----------------
    for (int t = 0; t < 8; ++t) {
        if (t < 7) wdma(t + 1);          // full phase of coverage
        if (t < 7) loadA(aB, 2 * t + 2);
        comp(0, t & 1);                  // chunk 2t   (Abuf0, W half 0)
        writeA(aA, 1);                   // chunk 2t+1 -> Abuf1
        __syncthreads();
        if (t < 7) loadA(aA, 2 * t + 3);
        comp(1, t & 1);                  // chunk 2t+1 (Abuf1, W half 1)
        if (t < 7) writeA(aB, 0);        // chunk 2t+2 -> Abuf0
        __syncthreads();
    }

    // ---------------- epilogue: bias + sigmoid + store ----------------
    const int wrow = row0 + wave * 16;
#pragma unroll
    for (int c = 0; c < 8; ++c) {
        const float bv = bias[c * 16 + r];
#pragma unroll
        for (int reg = 0; reg < 4; ++reg) {
            const int row = wrow + q * 4 + reg;
            float v = acc[c][reg] + bv;
            v = 1.0f / (1.0f + __expf(-v));
            out[(size_t)row * NT + c * 16 + r] = v;
        }
    }
}

extern "C" void kernel_launch(void* const* d_in, const int* in_sizes, int n_in,
                              void* d_out, int out_size, void* d_ws, size_t ws_size,
                              hipStream_t stream) {
    const float* x = (const float*)d_in[0];   // [32768,1024]
    const float* W = (const float*)d_in[1];   // [1024,128]
    const float* b = (const float*)d_in[2];   // [128]
    float* out     = (float*)d_out;           // [32768,128]
    __bf16* wsW    = (__bf16*)d_ws;           // 256 KB swizzled bf16 W

    prep_w<<<DIM * NT / 256, 256, 0, stream>>>(W, wsW);
    gemm_bias_sigmoid<<<BATCH / 128, 512, 0, stream>>>(
        x, (const __hip_bfloat16*)wsW, b, out);
}